// Round 3
// baseline (228.521 us; speedup 1.0000x reference)
//
#include <hip/hip_runtime.h>

#define DM 256
#define NMAX 64

// ws layout (floats):
//   bdc     [3][64][256]  off 0      : disk_b + disk_type + fourier(i) + rod_id(s) contributions
//   baseRod [3][256]      off 49152  : rod_b + rod_type + rod_id(r) contributions
//   rodTop  [65][256]     off 49920  : fourier(idx) @ rod_W[4..19]   (idx 64 = null_fourier)
//   rodBot  [65][256]     off 66560  : fourier(idx) @ rod_W[20..35]
#define OFF_BASEROD 49152
#define OFF_RODTOP  49920
#define OFF_RODBOT  66560

typedef float vf4 __attribute__((ext_vector_type(4)));

static __device__ __forceinline__ vf4 ld4(const float* p) {
  return *reinterpret_cast<const vf4*>(p);
}
static __device__ __forceinline__ void st4_nt(float* p, vf4 v) {
  __builtin_nontemporal_store(v, reinterpret_cast<vf4*>(p));
}

__global__ void precomp_kernel(
    const float* __restrict__ rod_id_embed,
    const float* __restrict__ disk_W,
    const float* __restrict__ disk_b,
    const float* __restrict__ rod_W,
    const float* __restrict__ rod_b,
    const float* __restrict__ null_fourier,
    float* __restrict__ ws) {
  const int idx = blockIdx.x;   // 0..64 (64 = null fourier row)
  const int d = threadIdx.x;    // 0..255

  float F[16];
  if (idx < 64) {
#pragma unroll
    for (int k = 0; k < 8; ++k) {
      float omega = powf(10000.0f, -(float)k * 0.125f);
      float a = (float)idx * omega;
      F[2 * k]     = sinf(a);
      F[2 * k + 1] = cosf(a);
    }
  } else {
#pragma unroll
    for (int k = 0; k < 16; ++k) F[k] = null_fourier[k];
  }

  float* bdc     = ws;
  float* baseRod = ws + OFF_BASEROD;
  float* rodTop  = ws + OFF_RODTOP;
  float* rodBot  = ws + OFF_RODBOT;

  float t = 0.f, bo = 0.f;
#pragma unroll
  for (int k = 0; k < 16; ++k) {
    t  += F[k] * rod_W[(4 + k) * DM + d];
    bo += F[k] * rod_W[(20 + k) * DM + d];
  }
  rodTop[idx * DM + d] = t;
  rodBot[idx * DM + d] = bo;

  if (idx < 64) {
    float base = disk_b[d] + disk_W[0 * DM + d];  // disk_type = [1,0]
#pragma unroll
    for (int k = 0; k < 16; ++k) base += F[k] * disk_W[(2 + k) * DM + d];
#pragma unroll
    for (int s = 0; s < 3; ++s) {
      float v = base;
#pragma unroll
      for (int j = 0; j < 8; ++j)
        v += rod_id_embed[s * 8 + j] * disk_W[(21 + j) * DM + d];
      bdc[(size_t)(s * 64 + idx) * DM + d] = v;
    }
  }
  if (idx < 3) {
    float br = rod_b[d] + rod_W[1 * DM + d];  // rod_type = [0,1]
#pragma unroll
    for (int j = 0; j < 8; ++j)
      br += rod_id_embed[idx * 8 + j] * rod_W[(36 + j) * DM + d];
    baseRod[idx * DM + d] = br;
  }
}

__launch_bounds__(256)
__global__ void enc_kernel(
    const int* __restrict__ state,
    const float* __restrict__ disk_W,
    const float* __restrict__ rod_W,
    const float* __restrict__ padding_embedding,
    const float* __restrict__ ws,
    float* __restrict__ out,
    int Btot) {
  const float* bdc     = ws;
  const float* baseRod = ws + OFF_BASEROD;
  const float* rodTop  = ws + OFF_RODTOP;
  const float* rodBot  = ws + OFF_RODBOT;

  const int w    = threadIdx.x >> 6;   // wave 0..3, one batch element each
  const int lane = threadIdx.x & 63;   // lane = disk position
  long b = (long)blockIdx.x * 4 + w;
  if (b >= Btot) b = Btot - 1;  // duplicate work, deterministic (B%4==0 normally)

  // meta: (code(+1 as float; 0 => padding), depth, is_top, is_bottom)
  __shared__ vf4 meta_sh[4][64];
  __shared__ float lnorm_sh[4][3];
  __shared__ float emp_sh[4][3];
  __shared__ int   ti_sh[4][3];
  __shared__ int   bi_sh[4][3];

  const int s = state[b * NMAX + lane];
  const bool valid = (s >= 0);
  const int ss = s <= 0 ? 0 : (s >= 2 ? 2 : s);  // state_safe = clip(s,0,2)
  const unsigned long long m0 = __ballot(valid && s == 0);
  const unsigned long long m1 = __ballot(valid && s == 1);
  const unsigned long long m2 = __ballot(valid && s == 2);
  const unsigned long long vm = __ballot(valid);
  const unsigned long long mym = (ss == 0) ? m0 : ((ss == 1) ? m1 : m2);
  const int above  = __popcll(mym & ((1ull << lane) - 1ull));
  const int height = __popcll(mym);

  vf4 md;
  md.x = valid ? (float)(ss + 1) : 0.f;
  md.y = (valid && height > 1) ? (float)above / (float)(height - 1) : 0.f;
  md.z = (valid && above == 0) ? 1.f : 0.f;
  md.w = (valid && above == height - 1) ? 1.f : 0.f;
  meta_sh[w][lane] = md;

  if (lane < 3) {
    const unsigned long long m = (lane == 0) ? m0 : ((lane == 1) ? m1 : m2);
    const int cnt = __popcll(m);
    const int lengths = __popcll(vm);
    lnorm_sh[w][lane] = (float)cnt / (float)(lengths > 1 ? lengths : 1);
    emp_sh[w][lane]   = (cnt == 0) ? 1.f : 0.f;
    ti_sh[w][lane]    = cnt ? (int)__builtin_ctzll(m) : 64;
    bi_sh[w][lane]    = cnt ? 63 - (int)__builtin_clzll(m) : 64;
  }
  __syncthreads();

  const int c0 = lane * 4;  // 4 consecutive columns per lane -> float4 IO
  const vf4 Wdep = ld4(disk_W + 18 * DM + c0);
  const vf4 Wt   = ld4(disk_W + 19 * DM + c0);
  const vf4 Wb   = ld4(disk_W + 20 * DM + c0);
  const vf4 pad  = ld4(padding_embedding + c0);
  const vf4 rW2  = ld4(rod_W + 2 * DM + c0);
  const vf4 rW3  = ld4(rod_W + 3 * DM + c0);

  float* outB = out + (size_t)b * 67 * DM;

#pragma unroll
  for (int r = 0; r < 3; ++r) {
    const float ln = lnorm_sh[w][r];
    const float em = emp_sh[w][r];
    const int ti = ti_sh[w][r];
    const int bi = bi_sh[w][r];
    vf4 v = ld4(baseRod + r * DM + c0);
    const vf4 tf = ld4(rodTop + (size_t)ti * DM + c0);
    const vf4 bf = ld4(rodBot + (size_t)bi * DM + c0);
    v += ln * rW2 + em * rW3 + tf + bf;
    st4_nt(outB + r * DM + c0, v);
  }

#pragma unroll 8
  for (int i = 0; i < 64; ++i) {
    const vf4 md2 = meta_sh[w][i];   // wave-uniform (LDS broadcast), 1 ds_read
    vf4 v;
    if (md2.x > 0.5f) {
      const int c = (int)md2.x - 1;
      const vf4 base = ld4(bdc + (size_t)(c * 64 + i) * DM + c0);
      v = base + md2.y * Wdep + md2.z * Wt + md2.w * Wb;
    } else {
      v = pad;
    }
    st4_nt(outB + (size_t)(3 + i) * DM + c0, v);
  }
}

extern "C" void kernel_launch(void* const* d_in, const int* in_sizes, int n_in,
                              void* d_out, int out_size, void* d_ws, size_t ws_size,
                              hipStream_t stream) {
  const int*   state             = (const int*)d_in[0];
  const float* rod_id_embed      = (const float*)d_in[1];
  const float* disk_W            = (const float*)d_in[2];
  const float* disk_b            = (const float*)d_in[3];
  const float* rod_W             = (const float*)d_in[4];
  const float* rod_b             = (const float*)d_in[5];
  const float* null_fourier      = (const float*)d_in[6];
  const float* padding_embedding = (const float*)d_in[7];
  float* ws  = (float*)d_ws;
  float* out = (float*)d_out;

  const int B = in_sizes[0] / NMAX;

  hipLaunchKernelGGL(precomp_kernel, dim3(65), dim3(256), 0, stream,
                     rod_id_embed, disk_W, disk_b, rod_W, rod_b, null_fourier, ws);
  hipLaunchKernelGGL(enc_kernel, dim3((B + 3) / 4), dim3(256), 0, stream,
                     state, disk_W, rod_W, padding_embedding, ws, out, B);
}

// Round 4
// 223.393 us; speedup vs baseline: 1.0230x; 1.0230x over previous
//
#include <hip/hip_runtime.h>

#define DM 256
#define NMAX 64

// ws layout (floats):
//   baseDisk [64][256]  off 0      : disk_b + disk_type + fourier(i) @ disk_W
//   ridproj  [3][256]   off 16384  : rod_id_embed[s] @ disk_W[21..28]
//   baseRod  [3][256]   off 17152  : rod_b + rod_type + rod_id(r) @ rod_W
//   rodTop   [65][256]  off 17920  : fourier(idx) @ rod_W[4..19]   (idx 64 = null_fourier)
//   rodBot   [65][256]  off 34560  : fourier(idx) @ rod_W[20..35]
#define OFF_RIDPROJ 16384
#define OFF_BASEROD 17152
#define OFF_RODTOP  17920
#define OFF_RODBOT  34560

typedef float vf4 __attribute__((ext_vector_type(4)));

static __device__ __forceinline__ vf4 ld4(const float* p) {
  return *reinterpret_cast<const vf4*>(p);
}
static __device__ __forceinline__ void st4_nt(float* p, vf4 v) {
  __builtin_nontemporal_store(v, reinterpret_cast<vf4*>(p));
}

__global__ void precomp_kernel(
    const float* __restrict__ rod_id_embed,
    const float* __restrict__ disk_W,
    const float* __restrict__ disk_b,
    const float* __restrict__ rod_W,
    const float* __restrict__ rod_b,
    const float* __restrict__ null_fourier,
    float* __restrict__ ws) {
  const int idx = blockIdx.x;   // 0..64 (64 = null fourier row)
  const int d = threadIdx.x;    // 0..255

  float F[16];
  if (idx < 64) {
#pragma unroll
    for (int k = 0; k < 8; ++k) {
      float omega = powf(10000.0f, -(float)k * 0.125f);
      float a = (float)idx * omega;
      F[2 * k]     = sinf(a);
      F[2 * k + 1] = cosf(a);
    }
  } else {
#pragma unroll
    for (int k = 0; k < 16; ++k) F[k] = null_fourier[k];
  }

  float* baseDisk = ws;
  float* ridproj  = ws + OFF_RIDPROJ;
  float* baseRod  = ws + OFF_BASEROD;
  float* rodTop   = ws + OFF_RODTOP;
  float* rodBot   = ws + OFF_RODBOT;

  float t = 0.f, bo = 0.f;
#pragma unroll
  for (int k = 0; k < 16; ++k) {
    t  += F[k] * rod_W[(4 + k) * DM + d];
    bo += F[k] * rod_W[(20 + k) * DM + d];
  }
  rodTop[idx * DM + d] = t;
  rodBot[idx * DM + d] = bo;

  if (idx < 64) {
    float base = disk_b[d] + disk_W[0 * DM + d];  // disk_type = [1,0]
#pragma unroll
    for (int k = 0; k < 16; ++k) base += F[k] * disk_W[(2 + k) * DM + d];
    baseDisk[(size_t)idx * DM + d] = base;
  }
  if (idx < 3) {
    float rp = 0.f;
    float br = rod_b[d] + rod_W[1 * DM + d];  // rod_type = [0,1]
#pragma unroll
    for (int j = 0; j < 8; ++j) {
      rp += rod_id_embed[idx * 8 + j] * disk_W[(21 + j) * DM + d];
      br += rod_id_embed[idx * 8 + j] * rod_W[(36 + j) * DM + d];
    }
    ridproj[idx * DM + d] = rp;
    baseRod[idx * DM + d] = br;
  }
}

#define BLK_B 8   // batch elements (waves) per block

__launch_bounds__(512)
__global__ void enc_kernel(
    const int* __restrict__ state,
    const float* __restrict__ disk_W,
    const float* __restrict__ rod_W,
    const float* __restrict__ padding_embedding,
    const float* __restrict__ ws,
    float* __restrict__ out,
    int Btot) {
  const float* baseDisk = ws;
  const float* ridproj  = ws + OFF_RIDPROJ;
  const float* baseRod  = ws + OFF_BASEROD;
  const float* rodTop   = ws + OFF_RODTOP;
  const float* rodBot   = ws + OFF_RODBOT;

  const int tid  = threadIdx.x;
  const int w    = tid >> 6;     // wave 0..7, one batch element each
  const int lane = tid & 63;     // lane = disk position
  long b = (long)blockIdx.x * BLK_B + w;
  if (b >= Btot) b = Btot - 1;   // duplicate work, deterministic (B%8==0 normally)

  __shared__ float base_sh[64 * DM];          // 64 KiB: the whole disk base table
  // meta: (code+1 as float; 0 => padding, depth, is_top, is_bottom)
  __shared__ vf4  meta_sh[BLK_B][64];
  __shared__ float lnorm_sh[BLK_B][3];
  __shared__ float emp_sh[BLK_B][3];
  __shared__ int   ti_sh[BLK_B][3];
  __shared__ int   bi_sh[BLK_B][3];

  // ---- stage baseDisk -> LDS (coalesced, 8 x vf4 per thread) ----
#pragma unroll
  for (int k = 0; k < 8; ++k) {
    const int i4 = tid + k * 512;  // vf4 index 0..4095
    *(reinterpret_cast<vf4*>(base_sh) + i4) = ld4(baseDisk + (size_t)i4 * 4);
  }

  // ---- per-batch combinatorics via ballot ----
  const int s = state[b * NMAX + lane];
  const bool valid = (s >= 0);
  const int ss = s <= 0 ? 0 : (s >= 2 ? 2 : s);  // state_safe = clip(s,0,2)
  const unsigned long long m0 = __ballot(valid && s == 0);
  const unsigned long long m1 = __ballot(valid && s == 1);
  const unsigned long long m2 = __ballot(valid && s == 2);
  const unsigned long long vm = __ballot(valid);
  const unsigned long long mym = (ss == 0) ? m0 : ((ss == 1) ? m1 : m2);
  const int above  = __popcll(mym & ((1ull << lane) - 1ull));
  const int height = __popcll(mym);

  vf4 md;
  md.x = valid ? (float)(ss + 1) : 0.f;
  md.y = (valid && height > 1) ? (float)above / (float)(height - 1) : 0.f;
  md.z = (valid && above == 0) ? 1.f : 0.f;
  md.w = (valid && above == height - 1) ? 1.f : 0.f;
  meta_sh[w][lane] = md;

  if (lane < 3) {
    const unsigned long long m = (lane == 0) ? m0 : ((lane == 1) ? m1 : m2);
    const int cnt = __popcll(m);
    const int lengths = __popcll(vm);
    lnorm_sh[w][lane] = (float)cnt / (float)(lengths > 1 ? lengths : 1);
    emp_sh[w][lane]   = (cnt == 0) ? 1.f : 0.f;
    ti_sh[w][lane]    = cnt ? (int)__builtin_ctzll(m) : 64;
    bi_sh[w][lane]    = cnt ? 63 - (int)__builtin_clzll(m) : 64;
  }
  __syncthreads();

  const int c0 = lane * 4;  // 4 consecutive columns per lane -> float4 IO
  const vf4 Wdep = ld4(disk_W + 18 * DM + c0);
  const vf4 Wt   = ld4(disk_W + 19 * DM + c0);
  const vf4 Wb   = ld4(disk_W + 20 * DM + c0);
  const vf4 pad  = ld4(padding_embedding + c0);
  const vf4 rW2  = ld4(rod_W + 2 * DM + c0);
  const vf4 rW3  = ld4(rod_W + 3 * DM + c0);
  const vf4 rp0  = ld4(ridproj + 0 * DM + c0);
  const vf4 rp1  = ld4(ridproj + 1 * DM + c0);
  const vf4 rp2  = ld4(ridproj + 2 * DM + c0);

  float* outB = out + (size_t)b * 67 * DM;

  // ---- rod rows (3 per batch element) ----
#pragma unroll
  for (int r = 0; r < 3; ++r) {
    const float ln = lnorm_sh[w][r];
    const float em = emp_sh[w][r];
    const int ti = ti_sh[w][r];
    const int bi = bi_sh[w][r];
    vf4 v = ld4(baseRod + r * DM + c0);
    const vf4 tf = ld4(rodTop + (size_t)ti * DM + c0);
    const vf4 bf = ld4(rodBot + (size_t)bi * DM + c0);
    v += ln * rW2 + em * rW3 + tf + bf;
    st4_nt(outB + r * DM + c0, v);
  }

  // ---- disk rows: pure LDS reads + FMA + NT store ----
#pragma unroll 8
  for (int i = 0; i < 64; ++i) {
    const vf4 md2 = meta_sh[w][i];   // wave-uniform broadcast, 1 ds_read
    vf4 v;
    if (md2.x > 0.5f) {
      const vf4 base = ld4(base_sh + i * DM + c0);  // conflict-free ds_read_b128
      const vf4 rp = (md2.x < 1.5f) ? rp0 : ((md2.x < 2.5f) ? rp1 : rp2);
      v = base + rp + md2.y * Wdep + md2.z * Wt + md2.w * Wb;
    } else {
      v = pad;
    }
    st4_nt(outB + (size_t)(3 + i) * DM + c0, v);
  }
}

extern "C" void kernel_launch(void* const* d_in, const int* in_sizes, int n_in,
                              void* d_out, int out_size, void* d_ws, size_t ws_size,
                              hipStream_t stream) {
  const int*   state             = (const int*)d_in[0];
  const float* rod_id_embed      = (const float*)d_in[1];
  const float* disk_W            = (const float*)d_in[2];
  const float* disk_b            = (const float*)d_in[3];
  const float* rod_W             = (const float*)d_in[4];
  const float* rod_b             = (const float*)d_in[5];
  const float* null_fourier      = (const float*)d_in[6];
  const float* padding_embedding = (const float*)d_in[7];
  float* ws  = (float*)d_ws;
  float* out = (float*)d_out;

  const int B = in_sizes[0] / NMAX;

  hipLaunchKernelGGL(precomp_kernel, dim3(65), dim3(256), 0, stream,
                     rod_id_embed, disk_W, disk_b, rod_W, rod_b, null_fourier, ws);
  hipLaunchKernelGGL(enc_kernel, dim3((B + BLK_B - 1) / BLK_B), dim3(512), 0, stream,
                     state, disk_W, rod_W, padding_embedding, ws, out, B);
}